// Round 9
// baseline (444.568 us; speedup 1.0000x reference)
//
#include <hip/hip_runtime.h>

#define B_  64
#define C_  32
#define N_  1152
#define DI_ 8
#define DC_ 16
#define NCH 3                // n's per staged chunk
#define NSLOT 128            // chunk-slots; slot handles chunks slot, +128, +256
#define STH 512              // 8 waves
#define NBLK 256             // 1 block/CU -> co-resident -> grid barrier safe

// zero the 16 grid-barrier slots (ws is re-poisoned 0xAA before every launch)
__global__ void caps_init(unsigned* __restrict__ bars) {
    if (threadIdx.x < 16) bars[threadIdx.x] = 0u;
}

// device-scope sense-free barrier: one fresh slot per sync point.
// All NBLK blocks are co-resident (1 block/CU, grid==CU count), so spinning
// cannot deadlock: no block waits on an undispatched block.
__device__ __forceinline__ void gridbar(unsigned* __restrict__ slot) {
    __syncthreads();
    if (threadIdx.x == 0) {
        __threadfence();                                   // release prior writes
        __hip_atomic_fetch_add(slot, 1u, __ATOMIC_ACQ_REL, __HIP_MEMORY_SCOPE_AGENT);
        while (__hip_atomic_load(slot, __ATOMIC_ACQUIRE, __HIP_MEMORY_SCOPE_AGENT) < NBLK)
            __builtin_amdgcn_s_sleep(1);
    }
    __syncthreads();
    __threadfence();                                       // acquire others' writes
}

// Fused persistent kernel: 3 routing passes, hat recomputed from LDS-staged W
// each pass (no 75.5 MB hat array: R8 moved it through L2-miss 3x = ~36us floor).
// block = bg(2) x slot(128); wave owns 4 b's (bq=4, R8's LDS-amplification fix);
// W frag quads XOR-swizzled (R5: 12.2M -> 2.4M conflict cycles).
__global__ __launch_bounds__(STH, 2) void caps_fused(
    const float* __restrict__ X, const float* __restrict__ W,
    float* __restrict__ p1, float* __restrict__ accb,
    float* __restrict__ out, unsigned* __restrict__ bars)
{
    __shared__ float wlds[NCH * 64 * 64];    // [nl][f=2c+h][phys quad q^(c&7)]
    __shared__ float xlds[NCH * 32 * 8];     // [nl][b_local 32][8]

    const int bg   = blockIdx.x & 1;
    const int slot = blockIdx.x >> 1;
    const int tid  = threadIdx.x;
    const int w    = tid >> 6;
    const int lane = tid & 63;
    const int c    = lane & 31;
    const int h    = lane >> 5;
    const int bl0  = w * 4;                  // wave's 4 local b's
    const int le   = 2 * c + h;
    const int sw   = c & 7;

    // embedded-reduce thread mapping (r1-style, 512 threads)
    const int rb = blockIdx.x >> 2;          // b
    const int rq = blockIdx.x & 3;           // e-quarter
    const int re = rq * 128 + (tid >> 2);    // e; within a wave: i = (lane>>2)&15
    const int rp = tid & 3;                  // 4-way slab split
    const float* rbase = p1 + (size_t)(rb >> 5) * NSLOT * 16384
                            + (size_t)(rb & 31) * 512 + re;

    for (int t = 0; t < 3; t++) {
        float areg[4][8];
        if (t > 0) {
#pragma unroll
            for (int bq = 0; bq < 4; bq++) {
                const float* ap = accb + (size_t)(bg * 32 + bl0 + bq) * 512 + le * 8;
                const float4 a0 = *(const float4*)ap;
                const float4 a1 = *(const float4*)(ap + 4);
                areg[bq][0]=a0.x; areg[bq][1]=a0.y; areg[bq][2]=a0.z; areg[bq][3]=a0.w;
                areg[bq][4]=a1.x; areg[bq][5]=a1.y; areg[bq][6]=a1.z; areg[bq][7]=a1.w;
            }
        }

        float acc[4][8];
#pragma unroll
        for (int bq = 0; bq < 4; bq++)
#pragma unroll
            for (int r = 0; r < 8; r++) acc[bq][r] = 0.f;

        for (int cc = 0; cc < 3; cc++) {
            if (cc) __syncthreads();         // drain readers before re-stage
            const int n0 = (slot + cc * NSLOT) * NCH;

            for (int G = tid; G < NCH * 1024; G += STH) {
                const int nl = G >> 10, f = (G >> 4) & 63, q = G & 15;
                const int wc = f >> 1, wh = f & 1;
                const float4 v = *(const float4*)(W + (size_t)(wc * N_ + n0 + nl) * 128 + wh * 64 + q * 4);
                *(float4*)(wlds + (nl * 64 + f) * 64 + (q ^ (wc & 7)) * 4) = v;
            }
            if (tid < NCH * 64) {
                const int nl = tid >> 6, bl = (tid >> 1) & 31, qx = tid & 1;
                const float4 v = *(const float4*)(X + (size_t)((bg * 32 + bl) * N_ + n0 + nl) * DI_ + qx * 4);
                *(float4*)(xlds + (nl * 32 + bl) * 8 + qx * 4) = v;
            }
            __syncthreads();

#pragma unroll
            for (int nl = 0; nl < NCH; nl++) {
                float4 xa[4], xb[4];
#pragma unroll
                for (int bq = 0; bq < 4; bq++) {
                    const float* xp = xlds + (nl * 32 + bl0 + bq) * 8;  // broadcast
                    xa[bq] = *(const float4*)xp;
                    xb[bq] = *(const float4*)(xp + 4);
                }
                float hat[4][8];
                const float* frag = wlds + (nl * 64 + le) * 64;
#pragma unroll
                for (int r = 0; r < 8; r++) {
                    const int pa = ((2 * r) ^ sw) * 4;
                    const int pb = pa ^ 4;
                    const float4 wa = *(const float4*)(frag + pa);
                    const float4 wb = *(const float4*)(frag + pb);
#pragma unroll
                    for (int bq = 0; bq < 4; bq++) {
                        hat[bq][r] = wa.x*xa[bq].x + wa.y*xa[bq].y + wa.z*xa[bq].z + wa.w*xa[bq].w
                                   + wb.x*xb[bq].x + wb.y*xb[bq].y + wb.z*xb[bq].z + wb.w*xb[bq].w;
                    }
                }
#pragma unroll
                for (int bq = 0; bq < 4; bq++) {
                    if (t > 0) {
                        float lg = hat[bq][0]*areg[bq][0] + hat[bq][1]*areg[bq][1]
                                 + hat[bq][2]*areg[bq][2] + hat[bq][3]*areg[bq][3]
                                 + hat[bq][4]*areg[bq][4] + hat[bq][5]*areg[bq][5]
                                 + hat[bq][6]*areg[bq][6] + hat[bq][7]*areg[bq][7];
                        lg += __shfl_xor(lg, 32, 64);    // combine i-halves (same c)
                        const float e = __expf(lg);      // no max-subtract: |lg| small
                        float s = e;
#pragma unroll
                        for (int m = 16; m >= 1; m >>= 1) s += __shfl_xor(s, m, 64);
                        const float sc = e * __builtin_amdgcn_rcpf(s);
#pragma unroll
                        for (int r = 0; r < 8; r++) acc[bq][r] += sc * hat[bq][r];
                    } else {
#pragma unroll
                        for (int r = 0; r < 8; r++) acc[bq][r] += hat[bq][r];
                    }
                }
            }
        }

        // slab write: [bg*128+slot][32 b][512 e]; t=0 folds softc=1/32
        const float f0 = (t == 0) ? 0.03125f : 1.0f;
        float* pout = p1 + (size_t)(bg * NSLOT + slot) * 16384;
#pragma unroll
        for (int bq = 0; bq < 4; bq++) {
            float* pb = pout + (bl0 + bq) * 512 + le * 8;
            *(float4*)pb       = make_float4(acc[bq][0]*f0, acc[bq][1]*f0, acc[bq][2]*f0, acc[bq][3]*f0);
            *(float4*)(pb + 4) = make_float4(acc[bq][4]*f0, acc[bq][5]*f0, acc[bq][6]*f0, acc[bq][7]*f0);
        }

        gridbar(bars + 2 * t);

        // embedded reduce + squash (every block: (b, e-quarter))
        {
            float v = 0.f;
#pragma unroll 8
            for (int ch = rp; ch < NSLOT; ch += 4)
                v += rbase[(size_t)ch * 16384];
            v += __shfl_xor(v, 1, 64);               // combine 4-way slab split
            v += __shfl_xor(v, 2, 64);
            float sq = v * v;
#pragma unroll
            for (int m = 4; m <= 32; m <<= 1) sq += __shfl_xor(sq, m, 64);  // sum over i
            const float scale = sq / (1.f + sq) * rsqrtf(sq + 1e-7f);
            const float ov = v * scale;
            if (rp == 0) {
                const int oidx = rb * 512 + re;
                if (t == 2) out[oidx] = ov;
                else        accb[oidx] = (t == 0) ? ov : (accb[oidx] + ov);
            }
        }

        if (t < 2) gridbar(bars + 2 * t + 1);        // accb visible before next pass
    }
}

extern "C" void kernel_launch(void* const* d_in, const int* in_sizes, int n_in,
                              void* d_out, int out_size, void* d_ws, size_t ws_size,
                              hipStream_t stream) {
    const float* X = (const float*)d_in[0];   // [B,N,DI]
    const float* W = (const float*)d_in[1];   // [C,N,DC,DI]
    float* out = (float*)d_out;               // [B,C,DC]

    char* ws = (char*)d_ws;
    float*    p1   = (float*)ws;                                  // 16,777,216 B
    float*    accb = (float*)(ws + (size_t)NBLK * 16384 * 4);     //    131,072 B
    unsigned* bars = (unsigned*)(ws + (size_t)NBLK * 16384 * 4 + (size_t)B_ * 512 * 4);

    caps_init <<<1, 64, 0, stream>>>(bars);
    caps_fused<<<NBLK, STH, 0, stream>>>(X, W, p1, accb, out, bars);
}

// Round 10
// 140.033 us; speedup vs baseline: 3.1747x; 3.1747x over previous
//
#include <hip/hip_runtime.h>
#include <hip/hip_fp16.h>

#define B_  64
#define C_  32
#define N_  1152
#define DI_ 8
#define DC_ 16
#define NCH 3                // n's per staged chunk
#define NSLOT 128            // chunk-slots; slot handles chunks slot, +128, +256
#define STH 512              // 8 waves
#define NOCT 16              // route n-groups (72 n each): 1024 blocks = 4/CU

static __device__ __forceinline__ unsigned pkh(float a, float b) {
    __half2 t = __float22half2_rn(make_float2(a, b));
    return *reinterpret_cast<unsigned*>(&t);
}
static __device__ __forceinline__ float2 uph(unsigned u) {
    __half2 h; *reinterpret_cast<unsigned*>(&h) = u;
    return __half22float2(h);
}

// ---------------- caps_hat: hat = W@x (fp32), store fp16, + s0 partials ----
// R9 lesson: grid-barrier fusion costs ~300us of spin on 8 XCDs — split
// kernels win. R8 hat was unoverlapped at 1 block/CU (LDS 8.6 + VALU 8 +
// write-drain 15 + fetch 3 ~= 35us serial). This round: bq=2 geometry
// (R5's 104-VGPR shape) -> grid 512 = bg(4) x slot(128) = 2 blocks/CU so
// one block's LDS/VALU overlaps the other's write-drain.
__global__ __launch_bounds__(STH, 2) void caps_hat(
    const float* __restrict__ X, const float* __restrict__ W,
    uint4* __restrict__ hatg, float* __restrict__ p1)
{
    __shared__ float wlds[NCH * 64 * 64];    // [nl][f=2c+h][phys quad q^(c&7)]
    __shared__ float xlds[NCH * 16 * 8];     // [nl][b_local 16][8]

    const int bg   = blockIdx.x & 3;
    const int slot = blockIdx.x >> 2;
    const int tid  = threadIdx.x;
    const int w    = tid >> 6;
    const int lane = tid & 63;
    const int c    = lane & 31;
    const int h    = lane >> 5;
    const int bl0  = w * 2;                  // wave's 2 local b's
    const int le   = 2 * c + h;
    const int sw   = c & 7;

    float acc[2][8];
#pragma unroll
    for (int bq = 0; bq < 2; bq++)
#pragma unroll
        for (int r = 0; r < 8; r++) acc[bq][r] = 0.f;

    for (int cc = 0; cc < 3; cc++) {
        if (cc) __syncthreads();             // drain readers before re-stage
        const int n0 = (slot + cc * NSLOT) * NCH;

        // stage W: (nl, f=2c+h, quad q) at phys quad q^(wc&7) — conflict-free reads
        for (int G = tid; G < NCH * 1024; G += STH) {
            const int nl = G >> 10, f = (G >> 4) & 63, q = G & 15;
            const int wc = f >> 1, wh = f & 1;
            const float4 v = *(const float4*)(W + (size_t)(wc * N_ + n0 + nl) * 128 + wh * 64 + q * 4);
            *(float4*)(wlds + (nl * 64 + f) * 64 + (q ^ (wc & 7)) * 4) = v;
        }
        // stage X: 16 b x NCH n
        if (tid < NCH * 32) {
            const int nl = tid >> 5, bl = (tid >> 1) & 15, qx = tid & 1;
            const float4 v = *(const float4*)(X + (size_t)((bg * 16 + bl) * N_ + n0 + nl) * DI_ + qx * 4);
            *(float4*)(xlds + (nl * 16 + bl) * 8 + qx * 4) = v;
        }
        __syncthreads();

#pragma unroll
        for (int nl = 0; nl < NCH; nl++) {
            float4 xa[2], xb[2];
#pragma unroll
            for (int bq = 0; bq < 2; bq++) {
                const float* xp = xlds + (nl * 16 + bl0 + bq) * 8;   // broadcast
                xa[bq] = *(const float4*)xp;
                xb[bq] = *(const float4*)(xp + 4);
            }
            uint4 hq[2];
            const float* frag = wlds + (nl * 64 + le) * 64;
#pragma unroll
            for (int rp = 0; rp < 4; rp++) {             // r-pairs
                const int r0 = 2 * rp, r1 = r0 + 1;
                const int pa0 = ((2 * r0) ^ sw) * 4;
                const int pb0 = pa0 ^ 4;
                const int pa1 = ((2 * r1) ^ sw) * 4;
                const int pb1 = pa1 ^ 4;
                const float4 wa0 = *(const float4*)(frag + pa0);
                const float4 wb0 = *(const float4*)(frag + pb0);
                const float4 wa1 = *(const float4*)(frag + pa1);
                const float4 wb1 = *(const float4*)(frag + pb1);
#pragma unroll
                for (int bq = 0; bq < 2; bq++) {
                    const float hv0 = wa0.x*xa[bq].x + wa0.y*xa[bq].y + wa0.z*xa[bq].z + wa0.w*xa[bq].w
                                    + wb0.x*xb[bq].x + wb0.y*xb[bq].y + wb0.z*xb[bq].z + wb0.w*xb[bq].w;
                    const float hv1 = wa1.x*xa[bq].x + wa1.y*xa[bq].y + wa1.z*xa[bq].z + wa1.w*xa[bq].w
                                    + wb1.x*xb[bq].x + wb1.y*xb[bq].y + wb1.z*xb[bq].z + wb1.w*xb[bq].w;
                    acc[bq][r0] += hv0;
                    acc[bq][r1] += hv1;
                    (&hq[bq].x)[rp] = pkh(hv0, hv1);
                }
            }
#pragma unroll
            for (int bq = 0; bq < 2; bq++) {
                const int b = bg * 16 + bl0 + bq;
                hatg[(size_t)(b * N_ + n0 + nl) * 64 + le] = hq[bq];
            }
        }
    }

    // p1 slab [bg*128+slot][16 b][512 e], e = c*16 + (h*8+r); softc=1/32 folded
    float* pout = p1 + (size_t)(bg * NSLOT + slot) * 8192;
#pragma unroll
    for (int bq = 0; bq < 2; bq++) {
        float* pb = pout + (bl0 + bq) * 512 + le * 8;
        *(float4*)pb       = make_float4(acc[bq][0]*0.03125f, acc[bq][1]*0.03125f,
                                         acc[bq][2]*0.03125f, acc[bq][3]*0.03125f);
        *(float4*)(pb + 4) = make_float4(acc[bq][4]*0.03125f, acc[bq][5]*0.03125f,
                                         acc[bq][6]*0.03125f, acc[bq][7]*0.03125f);
    }
}

// ---------------- caps_route: one routing pass over materialized fp16 hat --
// (unchanged from R8: 1024 blocks = 4/CU, software-pipelined k-loop)
__global__ __launch_bounds__(STH, 2) void caps_route(
    const uint4* __restrict__ hatg, const float* __restrict__ accb,
    float* __restrict__ p2)
{
    __shared__ float red[8 * 512];
    const int b    = blockIdx.x >> 4;
    const int oct  = blockIdx.x & 15;
    const int tid  = threadIdx.x;
    const int w    = tid >> 6;
    const int lane = tid & 63;
    const int c    = lane & 31;
    const int h    = lane >> 5;
    const int le   = 2 * c + h;

    const float* ap = accb + (size_t)b * 512 + le * 8;
    const float4 a0 = *(const float4*)ap;
    const float4 a1 = *(const float4*)(ap + 4);

    float acc[8] = {0.f,0.f,0.f,0.f,0.f,0.f,0.f,0.f};
    const uint4* hb = hatg + (size_t)(b * N_ + oct * 72) * 64 + le;

    uint4 v[2][3];
#pragma unroll
    for (int u = 0; u < 3; u++)
        v[0][u] = hb[(size_t)(w + 8 * u) * 64];

#pragma unroll
    for (int k = 0; k < 3; k++) {
        const int cur = k & 1, nxt = cur ^ 1;
        if (k < 2) {
#pragma unroll
            for (int u = 0; u < 3; u++)
                v[nxt][u] = hb[(size_t)(w + 8 * (3 * (k + 1) + u)) * 64];
        }
#pragma unroll
        for (int u = 0; u < 3; u++) {
            const float2 f0 = uph(v[cur][u].x);
            const float2 f1 = uph(v[cur][u].y);
            const float2 f2 = uph(v[cur][u].z);
            const float2 f3 = uph(v[cur][u].w);
            float lg = f0.x*a0.x + f0.y*a0.y + f1.x*a0.z + f1.y*a0.w
                     + f2.x*a1.x + f2.y*a1.y + f3.x*a1.z + f3.y*a1.w;
            lg += __shfl_xor(lg, 32, 64);        // combine i-halves (same c)
            const float e = __expf(lg);          // no max-subtract: |lg| small
            float s = e;
#pragma unroll
            for (int m = 16; m >= 1; m >>= 1) s += __shfl_xor(s, m, 64);
            const float sc = e * __builtin_amdgcn_rcpf(s);
            acc[0] += sc * f0.x; acc[1] += sc * f0.y;
            acc[2] += sc * f1.x; acc[3] += sc * f1.y;
            acc[4] += sc * f2.x; acc[5] += sc * f2.y;
            acc[6] += sc * f3.x; acc[7] += sc * f3.y;
        }
    }
    // block reduce over 8 waves
    *(float4*)(red + w * 512 + le * 8)     = make_float4(acc[0], acc[1], acc[2], acc[3]);
    *(float4*)(red + w * 512 + le * 8 + 4) = make_float4(acc[4], acc[5], acc[6], acc[7]);
    __syncthreads();
    float vs = 0.f;
#pragma unroll
    for (int s = 0; s < 8; s++) vs += red[s * 512 + tid];
    p2[(size_t)(b * NOCT + oct) * 512 + tid] = vs;
}

// ---------------- caps_r1: reduce 128 slot-slabs per (bg,b) ---------------
// p1 layout [bg4][slot128][16 b][512 e] — shared by hat and fallback paths.
__global__ __launch_bounds__(256) void caps_r1(
    const float* __restrict__ p1, float* __restrict__ accb,
    float* __restrict__ out, int t)
{
    const int b   = blockIdx.x >> 2;
    const int q   = blockIdx.x & 3;
    const int tid = threadIdx.x;
    const int e   = q * 128 + (tid >> 1);
    const int p   = tid & 1;
    const int bg  = b >> 4, bl = b & 15;
    const float* base = p1 + (size_t)bg * NSLOT * 8192 + (size_t)bl * 512 + e;
    float v = 0.f;
#pragma unroll 8
    for (int ch = p; ch < NSLOT; ch += 2)
        v += base[(size_t)ch * 8192];
    v += __shfl_xor(v, 1, 64);
    float sq = v * v;
#pragma unroll
    for (int m = 2; m <= 16; m <<= 1) sq += __shfl_xor(sq, m, 64);  // sum over i
    const float scale = sq / (1.f + sq) * rsqrtf(sq + 1e-7f);
    const float ov = v * scale;
    if (p == 0) {
        const int oidx = b * 512 + e;
        if (t == 2) out[oidx] = ov;
        else        accb[oidx] = (t == 0) ? ov : (accb[oidx] + ov);
    }
}

// ---------------- caps_r2: reduce caps_route's 16 oct-slabs per b ----------
__global__ __launch_bounds__(512) void caps_r2(
    const float* __restrict__ p2, float* __restrict__ accb,
    float* __restrict__ out, int t)
{
    const int b = blockIdx.x;
    const int e = threadIdx.x;               // [c=e>>4][i=e&15]
    const float* base = p2 + (size_t)b * (NOCT * 512) + e;
    float v = 0.f;
#pragma unroll
    for (int s = 0; s < NOCT; s++) v += base[s * 512];
    float sq = v * v;
#pragma unroll
    for (int m = 1; m <= 8; m <<= 1) sq += __shfl_xor(sq, m, 64);  // sum over i
    const float scale = sq / (1.f + sq) * rsqrtf(sq + 1e-7f);
    const float ov = v * scale;
    const int oidx = b * 512 + e;
    if (t == 2) out[oidx] = ov;
    else        accb[oidx] += ov;
}

// ---------------- fallback (R5 path, 16.9 MB ws) ---------------------------
__global__ __launch_bounds__(STH, 2) void caps_s_fb(
    const float* __restrict__ X, const float* __restrict__ W,
    const float* __restrict__ aout, float* __restrict__ partials, int t)
{
    __shared__ float wlds[NCH * 64 * 64];
    __shared__ float xlds[NCH * 16 * 8];
    const int bg = blockIdx.x & 3, slot = blockIdx.x >> 2;
    const int tid = threadIdx.x, w = tid >> 6, lane = tid & 63;
    const int c = lane & 31, h = lane >> 5, bl0 = w * 2, sw = c & 7;
    float areg[2][8] = {};
    if (t > 0) {
#pragma unroll
        for (int bq = 0; bq < 2; bq++) {
            const float* ap = aout + (size_t)(bg * 16 + bl0 + bq) * 512 + c * 16 + h * 8;
            const float4 a0 = *(const float4*)ap; const float4 a1 = *(const float4*)(ap + 4);
            areg[bq][0]=a0.x; areg[bq][1]=a0.y; areg[bq][2]=a0.z; areg[bq][3]=a0.w;
            areg[bq][4]=a1.x; areg[bq][5]=a1.y; areg[bq][6]=a1.z; areg[bq][7]=a1.w;
        }
    }
    float acc[2][8];
#pragma unroll
    for (int bq = 0; bq < 2; bq++)
#pragma unroll
        for (int r = 0; r < 8; r++) acc[bq][r] = 0.f;
    for (int cc = 0; cc < 3; cc++) {
        if (cc) __syncthreads();
        const int n0 = (slot + cc * NSLOT) * NCH;
        for (int G = tid; G < NCH * 1024; G += STH) {
            const int nl = G >> 10, f = (G >> 4) & 63, q = G & 15;
            const int wc = f >> 1, wh = f & 1;
            const float4 v = *(const float4*)(W + (size_t)(wc * N_ + n0 + nl) * 128 + wh * 64 + q * 4);
            *(float4*)(wlds + (nl * 64 + f) * 64 + (q ^ (wc & 7)) * 4) = v;
        }
        if (tid < NCH * 32) {
            const int nl = tid >> 5, bl = (tid >> 1) & 15, qx = tid & 1;
            const float4 v = *(const float4*)(X + (size_t)((bg * 16 + bl) * N_ + n0 + nl) * DI_ + qx * 4);
            *(float4*)(xlds + (nl * 16 + bl) * 8 + qx * 4) = v;
        }
        __syncthreads();
#pragma unroll
        for (int nl = 0; nl < NCH; nl++) {
            float4 xa[2], xb[2];
#pragma unroll
            for (int bq = 0; bq < 2; bq++) {
                const float* xp = xlds + (nl * 16 + bl0 + bq) * 8;
                xa[bq] = *(const float4*)xp; xb[bq] = *(const float4*)(xp + 4);
            }
            float hat[2][8];
            const float* frag = wlds + (nl * 64 + 2 * c + h) * 64;
#pragma unroll
            for (int r = 0; r < 8; r++) {
                const int pa = ((2 * r) ^ sw) * 4; const int pb = pa ^ 4;
                const float4 wa = *(const float4*)(frag + pa);
                const float4 wb = *(const float4*)(frag + pb);
#pragma unroll
                for (int bq = 0; bq < 2; bq++)
                    hat[bq][r] = wa.x*xa[bq].x + wa.y*xa[bq].y + wa.z*xa[bq].z + wa.w*xa[bq].w
                               + wb.x*xb[bq].x + wb.y*xb[bq].y + wb.z*xb[bq].z + wb.w*xb[bq].w;
            }
#pragma unroll
            for (int bq = 0; bq < 2; bq++) {
                float softc;
                if (t > 0) {
                    float lg = hat[bq][0]*areg[bq][0] + hat[bq][1]*areg[bq][1]
                             + hat[bq][2]*areg[bq][2] + hat[bq][3]*areg[bq][3]
                             + hat[bq][4]*areg[bq][4] + hat[bq][5]*areg[bq][5]
                             + hat[bq][6]*areg[bq][6] + hat[bq][7]*areg[bq][7];
                    lg += __shfl_xor(lg, 32, 64);
                    const float e = __expf(lg);
                    float s = e;
#pragma unroll
                    for (int m = 16; m >= 1; m >>= 1) s += __shfl_xor(s, m, 64);
                    softc = e / s;
                } else softc = 1.0f / 32.0f;
#pragma unroll
                for (int r = 0; r < 8; r++) acc[bq][r] += softc * hat[bq][r];
            }
        }
    }
    float* pout = partials + (size_t)(bg * NSLOT + slot) * 8192;
#pragma unroll
    for (int bq = 0; bq < 2; bq++) {
        float* pb = pout + (bl0 + bq) * 512 + c * 16 + h * 8;
        *(float4*)pb       = make_float4(acc[bq][0], acc[bq][1], acc[bq][2], acc[bq][3]);
        *(float4*)(pb + 4) = make_float4(acc[bq][4], acc[bq][5], acc[bq][6], acc[bq][7]);
    }
}

extern "C" void kernel_launch(void* const* d_in, const int* in_sizes, int n_in,
                              void* d_out, int out_size, void* d_ws, size_t ws_size,
                              hipStream_t stream) {
    const float* X = (const float*)d_in[0];   // [B,N,DI]
    const float* W = (const float*)d_in[1];   // [C,N,DC,DI]
    float* out = (float*)d_out;               // [B,C,DC]

    const size_t hat_b = (size_t)B_ * N_ * 512 * 2;      // 75,497,472 (fp16)
    const size_t p1_b  = (size_t)512 * 8192 * 4;         // 16,777,216
    const size_t p2_b  = (size_t)B_ * NOCT * 512 * 4;    //  2,097,152
    const size_t acc_b = (size_t)B_ * 512 * 4;           //    131,072

    if (ws_size >= hat_b + p1_b + p2_b + acc_b) {
        char* ws = (char*)d_ws;
        uint4* hatg = (uint4*)ws;
        float* p1   = (float*)(ws + hat_b);
        float* p2   = (float*)(ws + hat_b + p1_b);
        float* accb = (float*)(ws + hat_b + p1_b + p2_b);
        caps_hat  <<<512, STH, 0, stream>>>(X, W, hatg, p1);
        caps_r1   <<<256, 256, 0, stream>>>(p1, accb, out, 0);
        caps_route<<<B_ * NOCT, STH, 0, stream>>>(hatg, accb, p2);
        caps_r2   <<<64, 512, 0, stream>>>(p2, accb, out, 1);
        caps_route<<<B_ * NOCT, STH, 0, stream>>>(hatg, accb, p2);
        caps_r2   <<<64, 512, 0, stream>>>(p2, accb, out, 2);
    } else {
        float* p1 = (float*)d_ws;
        float* accb = p1 + (size_t)512 * 8192;
        for (int t = 0; t < 3; t++) {
            caps_s_fb<<<512, STH, 0, stream>>>(X, W, accb, p1, t);
            caps_r1  <<<256, 256, 0, stream>>>(p1, accb, out, t);
        }
    }
}

// Round 11
// 130.197 us; speedup vs baseline: 3.4146x; 1.0755x over previous
//
#include <hip/hip_runtime.h>
#include <hip/hip_fp16.h>

#define B_  64
#define C_  32
#define N_  1152
#define DI_ 8
#define DC_ 16
#define NCH 3                // fallback: n's per staged chunk
#define NSLOT 128            // fallback: chunk-slots
#define STH 512
#define NOCT 16              // route n-groups (72 n each): 1024 blocks

static __device__ __forceinline__ unsigned pkh(float a, float b) {
    __half2 t = __float22half2_rn(make_float2(a, b));
    return *reinterpret_cast<unsigned*>(&t);
}
static __device__ __forceinline__ float2 uph(unsigned u) {
    __half2 h; *reinterpret_cast<unsigned*>(&h) = u;
    return __half22float2(h);
}

// ---------------- caps_hat: n-major, barrier-free, register-held W ---------
// R10 post-mortem: bq=2 vs bq=4 identical (~48 us) -> hat was bound by
// barrier-chopped store drain (s_waitcnt vmcnt(0) at each __syncthreads waits
// on the hat stores; ~2 TB/s effective vs 6.3 TB/s fillBuffer ceiling).
// This kernel: block = one n, 64 threads. Lane (c,h) holds its 256-B W frag
// in 16 float4 REGS (64x b-amortization), X in 2 KB LDS, then a 64-b loop of
// pure FMA + one 1KB/wave coalesced hat store per b — stores flow freely.
__global__ __launch_bounds__(64) void caps_hat(
    const float* __restrict__ X, const float* __restrict__ W,
    uint4* __restrict__ hatg)
{
    __shared__ float xl[64 * 8];             // [b][8]
    const int n    = blockIdx.x;
    const int lane = threadIdx.x;
    const int c    = lane & 31;
    const int h    = lane >> 5;

    // stage X[b][:] (lane = b)
    {
        const float* xp = X + ((size_t)lane * N_ + n) * 8;
        *(float4*)(xl + lane * 8)     = *(const float4*)xp;
        *(float4*)(xl + lane * 8 + 4) = *(const float4*)(xp + 4);
    }
    // W frag -> regs: W[c][n][i=h*8+r][j], 16 consecutive float4
    float4 wr[16];
    const float* wp = W + ((size_t)c * N_ + n) * 128 + h * 64;
#pragma unroll
    for (int q = 0; q < 16; q++) wr[q] = *(const float4*)(wp + q * 4);
    __syncthreads();                          // 1-wave barrier: LDS visibility

    uint4* hout = hatg + (size_t)n * 64 + (2 * c + h);
#pragma unroll 4
    for (int b = 0; b < 64; b++) {
        const float4 xa = *(const float4*)(xl + b * 8);      // wave-uniform: broadcast
        const float4 xb = *(const float4*)(xl + b * 8 + 4);
        float hv[8];
#pragma unroll
        for (int r = 0; r < 8; r++) {
            const float4 wa = wr[2 * r], wb = wr[2 * r + 1];
            hv[r] = wa.x*xa.x + wa.y*xa.y + wa.z*xa.z + wa.w*xa.w
                  + wb.x*xb.x + wb.y*xb.y + wb.z*xb.z + wb.w*xb.w;
        }
        uint4 hq;
        hq.x = pkh(hv[0], hv[1]);
        hq.y = pkh(hv[2], hv[3]);
        hq.z = pkh(hv[4], hv[5]);
        hq.w = pkh(hv[6], hv[7]);
        hout[(size_t)b * (N_ * 64)] = hq;     // hat[(b*N+n)*64 + le], 1KB/wave coalesced
    }
}

// ---------------- caps_route: one pass over fp16 hat -----------------------
// mode 0: softc = 1/32 constant (computes s0 — replaces the old p1/r1 path).
// mode 1: inline softmax from accb. All 9 per-wave n-loads issued upfront
// (9 outstanding vs R8's 6; route was latency-bound at ~58 outstanding/CU).
__global__ __launch_bounds__(STH, 2) void caps_route(
    const uint4* __restrict__ hatg, const float* __restrict__ accb,
    float* __restrict__ p2, int mode, float postscale)
{
    __shared__ float red[8 * 512];
    const int b    = blockIdx.x >> 4;
    const int oct  = blockIdx.x & 15;
    const int tid  = threadIdx.x;
    const int w    = tid >> 6;
    const int lane = tid & 63;
    const int c    = lane & 31;
    const int h    = lane >> 5;
    const int le   = 2 * c + h;

    float4 a0 = make_float4(0.f,0.f,0.f,0.f), a1 = a0;
    if (mode) {
        const float* ap = accb + (size_t)b * 512 + le * 8;
        a0 = *(const float4*)ap;
        a1 = *(const float4*)(ap + 4);
    }

    const uint4* hb = hatg + ((size_t)b * N_ + oct * 72) * 64 + le;
    uint4 v[9];
#pragma unroll
    for (int idx = 0; idx < 9; idx++)
        v[idx] = hb[(size_t)(w + 8 * idx) * 64];     // n = oct*72 + w + 8*idx

    float acc[8] = {0.f,0.f,0.f,0.f,0.f,0.f,0.f,0.f};
#pragma unroll
    for (int idx = 0; idx < 9; idx++) {
        const float2 f0 = uph(v[idx].x);
        const float2 f1 = uph(v[idx].y);
        const float2 f2 = uph(v[idx].z);
        const float2 f3 = uph(v[idx].w);
        float sc;
        if (mode) {
            float lg = f0.x*a0.x + f0.y*a0.y + f1.x*a0.z + f1.y*a0.w
                     + f2.x*a1.x + f2.y*a1.y + f3.x*a1.z + f3.y*a1.w;
            lg += __shfl_xor(lg, 32, 64);            // combine i-halves (same c)
            const float e = __expf(lg);              // no max-subtract: |lg| small
            float s = e;
#pragma unroll
            for (int m = 16; m >= 1; m >>= 1) s += __shfl_xor(s, m, 64);
            sc = e * __builtin_amdgcn_rcpf(s);
        } else {
            sc = 1.0f;                               // 1/32 folded via postscale
        }
        acc[0] += sc * f0.x; acc[1] += sc * f0.y;
        acc[2] += sc * f1.x; acc[3] += sc * f1.y;
        acc[4] += sc * f2.x; acc[5] += sc * f2.y;
        acc[6] += sc * f3.x; acc[7] += sc * f3.y;
    }

    // block reduce over 8 waves
    *(float4*)(red + w * 512 + le * 8)     = make_float4(acc[0], acc[1], acc[2], acc[3]);
    *(float4*)(red + w * 512 + le * 8 + 4) = make_float4(acc[4], acc[5], acc[6], acc[7]);
    __syncthreads();
    float vs = 0.f;
#pragma unroll
    for (int s = 0; s < 8; s++) vs += red[s * 512 + tid];
    p2[(size_t)(b * NOCT + oct) * 512 + tid] = vs * postscale;
}

// ---------------- caps_r2: reduce 16 oct-slabs per b, squash ---------------
__global__ __launch_bounds__(512) void caps_r2(
    const float* __restrict__ p2, float* __restrict__ accb,
    float* __restrict__ out, int t)
{
    const int b = blockIdx.x;
    const int e = threadIdx.x;               // [c=e>>4][i=e&15]
    const float* base = p2 + (size_t)b * (NOCT * 512) + e;
    float v = 0.f;
#pragma unroll
    for (int s = 0; s < NOCT; s++) v += base[s * 512];
    float sq = v * v;
#pragma unroll
    for (int m = 1; m <= 8; m <<= 1) sq += __shfl_xor(sq, m, 64);  // sum over i
    const float scale = sq / (1.f + sq) * rsqrtf(sq + 1e-7f);
    const float ov = v * scale;
    const int oidx = b * 512 + e;
    if (t == 2)      out[oidx]  = ov;
    else if (t == 0) accb[oidx] = ov;        // accb starts poisoned: write, not +=
    else             accb[oidx] += ov;
}

// ---------------- fallback (R5 path, 16.9 MB ws) ---------------------------
__global__ __launch_bounds__(STH, 2) void caps_s_fb(
    const float* __restrict__ X, const float* __restrict__ W,
    const float* __restrict__ aout, float* __restrict__ partials, int t)
{
    __shared__ float wlds[NCH * 64 * 64];
    __shared__ float xlds[NCH * 16 * 8];
    const int bg = blockIdx.x & 3, slot = blockIdx.x >> 2;
    const int tid = threadIdx.x, w = tid >> 6, lane = tid & 63;
    const int c = lane & 31, h = lane >> 5, bl0 = w * 2, sw = c & 7;
    float areg[2][8] = {};
    if (t > 0) {
#pragma unroll
        for (int bq = 0; bq < 2; bq++) {
            const float* ap = aout + (size_t)(bg * 16 + bl0 + bq) * 512 + c * 16 + h * 8;
            const float4 a0 = *(const float4*)ap; const float4 a1 = *(const float4*)(ap + 4);
            areg[bq][0]=a0.x; areg[bq][1]=a0.y; areg[bq][2]=a0.z; areg[bq][3]=a0.w;
            areg[bq][4]=a1.x; areg[bq][5]=a1.y; areg[bq][6]=a1.z; areg[bq][7]=a1.w;
        }
    }
    float acc[2][8];
#pragma unroll
    for (int bq = 0; bq < 2; bq++)
#pragma unroll
        for (int r = 0; r < 8; r++) acc[bq][r] = 0.f;
    for (int cc = 0; cc < 3; cc++) {
        if (cc) __syncthreads();
        const int n0 = (slot + cc * NSLOT) * NCH;
        for (int G = tid; G < NCH * 1024; G += STH) {
            const int nl = G >> 10, f = (G >> 4) & 63, q = G & 15;
            const int wc = f >> 1, wh = f & 1;
            const float4 v = *(const float4*)(W + (size_t)(wc * N_ + n0 + nl) * 128 + wh * 64 + q * 4);
            *(float4*)(wlds + (nl * 64 + f) * 64 + (q ^ (wc & 7)) * 4) = v;
        }
        if (tid < NCH * 32) {
            const int nl = tid >> 5, bl = (tid >> 1) & 15, qx = tid & 1;
            const float4 v = *(const float4*)(X + (size_t)((bg * 16 + bl) * N_ + n0 + nl) * DI_ + qx * 4);
            *(float4*)(xlds + (nl * 16 + bl) * 8 + qx * 4) = v;
        }
        __syncthreads();
#pragma unroll
        for (int nl = 0; nl < NCH; nl++) {
            float4 xa[2], xb[2];
#pragma unroll
            for (int bq = 0; bq < 2; bq++) {
                const float* xp = xlds + (nl * 16 + bl0 + bq) * 8;
                xa[bq] = *(const float4*)xp; xb[bq] = *(const float4*)(xp + 4);
            }
            float hat[2][8];
            const float* frag = wlds + (nl * 64 + 2 * c + h) * 64;
#pragma unroll
            for (int r = 0; r < 8; r++) {
                const int pa = ((2 * r) ^ sw) * 4; const int pb = pa ^ 4;
                const float4 wa = *(const float4*)(frag + pa);
                const float4 wb = *(const float4*)(frag + pb);
#pragma unroll
                for (int bq = 0; bq < 2; bq++)
                    hat[bq][r] = wa.x*xa[bq].x + wa.y*xa[bq].y + wa.z*xa[bq].z + wa.w*xa[bq].w
                               + wb.x*xb[bq].x + wb.y*xb[bq].y + wb.z*xb[bq].z + wb.w*xb[bq].w;
            }
#pragma unroll
            for (int bq = 0; bq < 2; bq++) {
                float softc;
                if (t > 0) {
                    float lg = hat[bq][0]*areg[bq][0] + hat[bq][1]*areg[bq][1]
                             + hat[bq][2]*areg[bq][2] + hat[bq][3]*areg[bq][3]
                             + hat[bq][4]*areg[bq][4] + hat[bq][5]*areg[bq][5]
                             + hat[bq][6]*areg[bq][6] + hat[bq][7]*areg[bq][7];
                    lg += __shfl_xor(lg, 32, 64);
                    const float e = __expf(lg);
                    float s = e;
#pragma unroll
                    for (int m = 16; m >= 1; m >>= 1) s += __shfl_xor(s, m, 64);
                    softc = e / s;
                } else softc = 1.0f / 32.0f;
#pragma unroll
                for (int r = 0; r < 8; r++) acc[bq][r] += softc * hat[bq][r];
            }
        }
    }
    float* pout = partials + (size_t)(bg * NSLOT + slot) * 8192;
#pragma unroll
    for (int bq = 0; bq < 2; bq++) {
        float* pb = pout + (bl0 + bq) * 512 + c * 16 + h * 8;
        *(float4*)pb       = make_float4(acc[bq][0], acc[bq][1], acc[bq][2], acc[bq][3]);
        *(float4*)(pb + 4) = make_float4(acc[bq][4], acc[bq][5], acc[bq][6], acc[bq][7]);
    }
}

__global__ __launch_bounds__(256) void caps_r1_fb(
    const float* __restrict__ p1, float* __restrict__ accb,
    float* __restrict__ out, int t)
{
    const int b   = blockIdx.x >> 2;
    const int q   = blockIdx.x & 3;
    const int tid = threadIdx.x;
    const int e   = q * 128 + (tid >> 1);
    const int p   = tid & 1;
    const int bg  = b >> 4, bl = b & 15;
    const float* base = p1 + (size_t)bg * NSLOT * 8192 + (size_t)bl * 512 + e;
    float v = 0.f;
#pragma unroll 8
    for (int ch = p; ch < NSLOT; ch += 2)
        v += base[(size_t)ch * 8192];
    v += __shfl_xor(v, 1, 64);
    float sq = v * v;
#pragma unroll
    for (int m = 2; m <= 16; m <<= 1) sq += __shfl_xor(sq, m, 64);
    const float scale = sq / (1.f + sq) * rsqrtf(sq + 1e-7f);
    const float ov = v * scale;
    if (p == 0) {
        const int oidx = b * 512 + e;
        if (t == 2) out[oidx] = ov;
        else        accb[oidx] = (t == 0) ? ov : (accb[oidx] + ov);
    }
}

extern "C" void kernel_launch(void* const* d_in, const int* in_sizes, int n_in,
                              void* d_out, int out_size, void* d_ws, size_t ws_size,
                              hipStream_t stream) {
    const float* X = (const float*)d_in[0];   // [B,N,DI]
    const float* W = (const float*)d_in[1];   // [C,N,DC,DI]
    float* out = (float*)d_out;               // [B,C,DC]

    const size_t hat_b = (size_t)B_ * N_ * 512 * 2;      // 75,497,472 (fp16)
    const size_t p2_b  = (size_t)B_ * NOCT * 512 * 4;    //  2,097,152
    const size_t acc_b = (size_t)B_ * 512 * 4;           //    131,072

    if (ws_size >= hat_b + p2_b + acc_b) {
        char* ws = (char*)d_ws;
        uint4* hatg = (uint4*)ws;
        float* p2   = (float*)(ws + hat_b);
        float* accb = (float*)(ws + hat_b + p2_b);
        caps_hat  <<<N_, 64, 0, stream>>>(X, W, hatg);
        caps_route<<<B_ * NOCT, STH, 0, stream>>>(hatg, accb, p2, 0, 0.03125f);
        caps_r2   <<<B_, 512, 0, stream>>>(p2, accb, out, 0);
        caps_route<<<B_ * NOCT, STH, 0, stream>>>(hatg, accb, p2, 1, 1.0f);
        caps_r2   <<<B_, 512, 0, stream>>>(p2, accb, out, 1);
        caps_route<<<B_ * NOCT, STH, 0, stream>>>(hatg, accb, p2, 1, 1.0f);
        caps_r2   <<<B_, 512, 0, stream>>>(p2, accb, out, 2);
    } else {
        float* p1 = (float*)d_ws;             // 16.8 MB
        float* accb = p1 + (size_t)512 * 8192;
        for (int t = 0; t < 3; t++) {
            caps_s_fb<<<512, STH, 0, stream>>>(X, W, accb, p1, t);
            caps_r1_fb<<<256, 256, 0, stream>>>(p1, accb, out, t);
        }
    }
}